// Round 1
// baseline (960.611 us; speedup 1.0000x reference)
//
#include <hip/hip_runtime.h>
#include <stdint.h>

#define N_USERS 100000
#define N_ITEMS 50000
#define NTOT    150000
#define DIM     64
#define NNZ     2000000
#define NHOPS   3

// ---------------- Threefry-2x32, 20 rounds (JAX-compatible) ----------------
__host__ __device__ inline void tf2x32(uint32_t k0, uint32_t k1,
                                       uint32_t x0, uint32_t x1,
                                       uint32_t& o0, uint32_t& o1) {
  uint32_t ks2 = k0 ^ k1 ^ 0x1BD11BDAu;
  x0 += k0; x1 += k1;
#define ROTL(x,r) (((x) << (r)) | ((x) >> (32 - (r))))
#define RND(r) { x0 += x1; x1 = ROTL(x1, r); x1 ^= x0; }
  RND(13) RND(15) RND(26) RND(6)
  x0 += k1;  x1 += ks2 + 1u;
  RND(17) RND(29) RND(16) RND(24)
  x0 += ks2; x1 += k0 + 2u;
  RND(13) RND(15) RND(26) RND(6)
  x0 += k0;  x1 += k1 + 3u;
  RND(17) RND(29) RND(16) RND(24)
  x0 += k1;  x1 += ks2 + 4u;
  RND(13) RND(15) RND(26) RND(6)
  x0 += ks2; x1 += k0 + 5u;
  o0 = x0; o1 = x1;
#undef RND
#undef ROTL
}

// jax_threefry_partitionable=True random bits for flat element idx:
// bits = b1 ^ b2 of threefry(key, hi32(idx)=0, lo32(idx)=idx)
__device__ inline float tf_uniform(uint32_t k0, uint32_t k1, uint32_t idx) {
  uint32_t b1, b2;
  tf2x32(k0, k1, 0u, idx, b1, b2);
  uint32_t bits = b1 ^ b2;
  return __uint_as_float((bits >> 9) | 0x3f800000u) - 1.0f;
}

// ---------------- kernels ----------------
// out layout: [n][hop(0..3)][d] float32 (== reference stack axis=1)

// write hop0 = concat(user,item); zero hop slots 1..3
__global__ __launch_bounds__(256) void k_init(const float4* __restrict__ user,
                                              const float4* __restrict__ item,
                                              float4* __restrict__ out) {
  int idx = blockIdx.x * 256 + threadIdx.x;      // over NTOT*16 float4s
  if (idx >= NTOT * 16) return;
  int n = idx >> 4;
  float4 v = (n < N_USERS) ? user[idx] : item[idx - N_USERS * 16];
  float4 z = make_float4(0.f, 0.f, 0.f, 0.f);
  float4* o = out + (size_t)n * 64 + (idx & 15); // row n = 64 float4s, hop h at +h*16
  o[0] = v; o[16] = z; o[32] = z; o[48] = z;
}

// one wave per edge: edge dropout (Threefry) + gather + atomic scatter-add
__global__ __launch_bounds__(256) void k_spmm(const float* __restrict__ vals,
                                              const int* __restrict__ rows,
                                              const int* __restrict__ cols,
                                              float* __restrict__ out,
                                              int hop, uint32_t ke0, uint32_t ke1) {
  int gid = blockIdx.x * 256 + threadIdx.x;
  int e = gid >> 6;
  if (e >= NNZ) return;
  int lane = threadIdx.x & 63;
  float u = tf_uniform(ke0, ke1, (uint32_t)e);
  // reference: keep iff floor(0.5 + u) == 1  <=>  (0.5f + u) >= 1.0f  (match fp exactly)
  if (!(0.5f + u >= 1.0f)) return;
  float v = vals[e] * 2.0f;                       // 1/(1-EDGE_RATE) = 2
  int r = rows[e], c = cols[e];
  const float* src = out + ((size_t)c * 4 + hop) * 64;
  float*       dst = out + ((size_t)r * 4 + hop + 1) * 64;
  atomicAdd(dst + lane, v * src[lane]);
}

// inverted message dropout, in place on hop+1 slice
__global__ __launch_bounds__(256) void k_mdrop(float* __restrict__ out,
                                               int hop, uint32_t km0, uint32_t km1) {
  int idx = blockIdx.x * 256 + threadIdx.x;      // flat over (NTOT, DIM)
  if (idx >= NTOT * DIM) return;
  float u = tf_uniform(km0, km1, (uint32_t)idx);
  int n = idx >> 6, d = idx & 63;
  float* p = out + ((size_t)n * 4 + hop + 1) * 64 + d;
  float val = *p;
  *p = (u < 0.9f) ? val * (float)(1.0 / 0.9) : 0.0f;
}

// ---------------- launch ----------------
extern "C" void kernel_launch(void* const* d_in, const int* in_sizes, int n_in,
                              void* d_out, int out_size, void* d_ws, size_t ws_size,
                              hipStream_t stream) {
  const float* user = (const float*)d_in[0];
  const float* item = (const float*)d_in[1];
  const float* vals = (const float*)d_in[2];
  const int*   rows = (const int*)d_in[3];
  const int*   cols = (const int*)d_in[4];
  float* out = (float*)d_out;

  // host-side key schedule: key(42) -> per-hop (dkey, ke, km) via fold-like split
  uint32_t k0 = 0u, k1 = 42u;
  uint32_t ke[NHOPS][2], km[NHOPS][2];
  for (int h = 0; h < NHOPS; ++h) {
    uint32_t nk0, nk1;
    tf2x32(k0, k1, 0u, 0u, nk0, nk1);          // keys[0] -> new dkey
    tf2x32(k0, k1, 0u, 1u, ke[h][0], ke[h][1]); // keys[1] -> edge-dropout key
    tf2x32(k0, k1, 0u, 2u, km[h][0], km[h][1]); // keys[2] -> message-dropout key
    k0 = nk0; k1 = nk1;
  }

  k_init<<<(NTOT * 16 + 255) / 256, 256, 0, stream>>>(
      (const float4*)user, (const float4*)item, (float4*)out);

  for (int h = 0; h < NHOPS; ++h) {
    k_spmm<<<(NNZ * 64) / 256, 256, 0, stream>>>(vals, rows, cols, out, h,
                                                 ke[h][0], ke[h][1]);
    k_mdrop<<<(NTOT * DIM + 255) / 256, 256, 0, stream>>>(out, h,
                                                          km[h][0], km[h][1]);
  }
}